// Round 1
// baseline (1234.818 us; speedup 1.0000x reference)
//
#include <hip/hip_runtime.h>
#include <cstdint>
#include <cmath>

#define NB 4
#define NS 2048
#define ND 2048
#define NH 16
#define NDH 128
#define NM (NB*NS)   // 8192

typedef unsigned short u16;
typedef __bf16 bf16x8 __attribute__((ext_vector_type(8)));
typedef u16    u16x8  __attribute__((ext_vector_type(8)));
typedef float  f32x4  __attribute__((ext_vector_type(4)));

__device__ __forceinline__ u16 f2bf(float f) {
  unsigned u = __float_as_uint(f);
  u += 0x7fffu + ((u >> 16) & 1u);   // RNE
  return (u16)(u >> 16);
}
__device__ __forceinline__ float bf2f(u16 h) {
  return __uint_as_float(((unsigned)h) << 16);
}
__device__ __forceinline__ void gld16(const void* g, void* l) {
  __builtin_amdgcn_global_load_lds((__attribute__((address_space(1))) void*)g,
                                   (__attribute__((address_space(3))) void*)l,
                                   16, 0, 0);
}
__device__ __forceinline__ f32x4 mfma_bf16(bf16x8 a, bf16x8 b, f32x4 c) {
  return __builtin_amdgcn_mfma_f32_16x16x32_bf16(a, b, c, 0, 0, 0);
}

// ---------------- fp32 -> bf16 convert (8 elems/thread) ----------------
__global__ void cvt_bf16_kernel(const float* __restrict__ in, u16* __restrict__ out, int n8) {
  int i = blockIdx.x * 256 + threadIdx.x;
  if (i >= n8) return;
  const float4* p = (const float4*)in + (size_t)i * 2;
  float4 a = p[0], b = p[1];
  u16x8 r;
  r[0]=f2bf(a.x); r[1]=f2bf(a.y); r[2]=f2bf(a.z); r[3]=f2bf(a.w);
  r[4]=f2bf(b.x); r[5]=f2bf(b.y); r[6]=f2bf(b.z); r[7]=f2bf(b.w);
  ((u16x8*)out)[i] = r;
}

// ---------------- RoPE tables: cos/sin [S][64] ----------------
__global__ void rope_tables_kernel(float* __restrict__ cosT, float* __restrict__ sinT) {
  int s = blockIdx.x, d = threadIdx.x;   // grid (NS), block (64)
  double inv = pow(10000.0, -(double)d / 64.0);
  float ang = (float)((double)s * inv);
  cosT[s*64 + d] = cosf(ang);
  sinT[s*64 + d] = sinf(ang);
}

// ---------------- RoPE apply, in place on bf16 [NM][ND] ----------------
// thread handles 8 pairs: (d0..d0+7, d0+64..d0+71) of one (row, head)
__global__ void rope_apply_kernel(u16* __restrict__ X, const float* __restrict__ cosT,
                                  const float* __restrict__ sinT) {
  int idx = blockIdx.x * 256 + threadIdx.x;          // NM*NH*8 total
  int pc = idx & 7, h = (idx >> 3) & (NH - 1), m = idx >> 7;
  int s = m & (NS - 1);
  int d0 = pc * 8;
  size_t base = (size_t)m * ND + h * NDH + d0;
  u16x8 v0 = *(const u16x8*)(X + base);
  u16x8 v1 = *(const u16x8*)(X + base + 64);
  u16x8 r0, r1;
#pragma unroll
  for (int j = 0; j < 8; ++j) {
    float c  = cosT[s*64 + d0 + j];
    float sn = sinT[s*64 + d0 + j];
    float x0 = bf2f(v0[j]), x1 = bf2f(v1[j]);
    r0[j] = f2bf(x0 * c - x1 * sn);
    r1[j] = f2bf(x1 * c + x0 * sn);
  }
  *(u16x8*)(X + base)      = r0;
  *(u16x8*)(X + base + 64) = r1;
}

// ---------------- bf16 GEMM: C[M,N] = A[M,K] * Bw[N,K]^T ----------------
// m97 structure: 128x128 tile, BK=32, 4 waves (each 64x64), global_load_lds w16
template <typename OutT>
__global__ __launch_bounds__(256) void gemm_bt_kernel(
    const u16* __restrict__ A, const u16* __restrict__ Bw, OutT* __restrict__ C,
    int Nd, int Kd) {
  __shared__ __align__(16) u16 As[128*32];
  __shared__ __align__(16) u16 Bs[128*32];
  int tid = threadIdx.x;
  int wave = tid >> 6, lane = tid & 63;
  int li = lane & 15, lg = lane >> 4;
  int NT = Nd >> 7;
  int cpx = gridDim.x >> 3;                      // grid multiple of 8
  int bid = blockIdx.x;
  int swz = (bid & 7) * cpx + (bid >> 3);        // XCD-aware swizzle (bijective)
  int m0 = (swz / NT) << 7, n0 = (swz % NT) << 7;
  int wr = wave >> 1, wc = wave & 1;
  f32x4 acc[4][4] = {};
  const u16* Ap = A  + (size_t)(m0 + (lane >> 2)) * Kd + (lane & 3) * 8;
  const u16* Bp = Bw + (size_t)(n0 + (lane >> 2)) * Kd + (lane & 3) * 8;
  int fo = lg * 8;
  for (int k0 = 0; k0 < Kd; k0 += 32) {
#pragma unroll
    for (int it = 0; it < 2; ++it) {
      int c = it*4 + wave;                       // 8 chunks of 16 rows
      gld16(Ap + (size_t)c*16*Kd + k0, &As[c*512]);
      gld16(Bp + (size_t)c*16*Kd + k0, &Bs[c*512]);
    }
    __syncthreads();
    bf16x8 af[4], bfr[4];
#pragma unroll
    for (int i = 0; i < 4; ++i) {
      af[i]  = *(const bf16x8*)&As[(wr*64 + i*16 + li)*32 + fo];
      bfr[i] = *(const bf16x8*)&Bs[(wc*64 + i*16 + li)*32 + fo];
    }
#pragma unroll
    for (int i = 0; i < 4; ++i)
#pragma unroll
      for (int j = 0; j < 4; ++j)
        acc[i][j] = mfma_bf16(af[i], bfr[j], acc[i][j]);
    __syncthreads();
  }
  // C layout: col = lane&15, row = (lane>>4)*4 + reg  [verified m89/m91]
  int rbase = m0 + wr*64 + lg*4;
  int cbase = n0 + wc*64 + li;
#pragma unroll
  for (int i = 0; i < 4; ++i)
#pragma unroll
    for (int j = 0; j < 4; ++j)
#pragma unroll
      for (int r = 0; r < 4; ++r) {
        size_t off = (size_t)(rbase + i*16 + r) * Nd + (cbase + j*16);
        if constexpr (sizeof(OutT) == 2) C[off] = f2bf(acc[i][j][r]);
        else                             C[off] = acc[i][j][r];
      }
}

// ---------------- causal flash attention ----------------
// grid (S/64, B*H), 256 threads; wave wv owns q rows [q0+wv*16, +16)
__global__ __launch_bounds__(256) void flash_attn_kernel(
    const u16* __restrict__ Q, const u16* __restrict__ K, const u16* __restrict__ V,
    u16* __restrict__ O) {
  __shared__ __align__(16) u16 Ks[64*128];   // swizzled row-major [kv][dh]
  __shared__ __align__(16) u16 Vt[128*64];   // swizzled transposed [dh][kv]
  __shared__ __align__(16) u16 Pl[4][16*64]; // per-wave P bounce
  int tid = threadIdx.x, wv = tid >> 6, lane = tid & 63;
  int li = lane & 15, lg = lane >> 4;
  int b = blockIdx.y >> 4, h = blockIdx.y & 15;
  int q0 = blockIdx.x << 6;
  const float scale = 0.08838834764831845f;  // 1/sqrt(128)

  bf16x8 qf[4];
  {
    const u16* qp = Q + (size_t)(b*NS + q0 + wv*16 + li) * ND + h*NDH + lg*8;
#pragma unroll
    for (int kk = 0; kk < 4; ++kk) qf[kk] = *(const bf16x8*)(qp + kk*32);
  }
  f32x4 o[8] = {};
  float m_run[4], l_run[4];
#pragma unroll
  for (int r = 0; r < 4; ++r) { m_run[r] = -INFINITY; l_run[r] = 0.f; }

  for (int kv0 = 0; kv0 <= q0; kv0 += 64) {
    __syncthreads();
    // ---- stage K [64][128] (XOR-swz) and V^T [128][64] (XOR-swz) ----
#pragma unroll
    for (int it = 0; it < 4; ++it) {
      int c = it*256 + tid;
      int row = c >> 4, colc = (c & 15) * 8;
      size_t gro = (size_t)(b*NS + kv0 + row) * ND + h*NDH + colc;
      u16x8 kv8 = *(const u16x8*)(K + gro);
      int kb = (row*256 + colc*2) ^ ((row & 7) << 4);
      *(u16x8*)((char*)Ks + kb) = kv8;
      u16x8 vv8 = *(const u16x8*)(V + gro);
#pragma unroll
      for (int j = 0; j < 8; ++j) {
        int dh = colc + j;
        int vb = (dh*128 + row*2) ^ ((dh & 7) << 4);
        *(u16*)((char*)Vt + vb) = vv8[j];
      }
    }
    __syncthreads();

    // ---- S = Q K^T (16q x 64kv per wave) ----
    f32x4 sc[4] = {};
#pragma unroll
    for (int ni = 0; ni < 4; ++ni) {
      int row = ni*16 + li;
#pragma unroll
      for (int kk = 0; kk < 4; ++kk) {
        int kb = (row*256 + (kk*32 + lg*8)*2) ^ ((row & 7) << 4);
        bf16x8 kf = *(const bf16x8*)((char*)Ks + kb);
        sc[ni] = mfma_bf16(qf[kk], kf, sc[ni]);
      }
    }
    bool diag = (kv0 == q0);
    float mt[4] = {-INFINITY, -INFINITY, -INFINITY, -INFINITY};
#pragma unroll
    for (int ni = 0; ni < 4; ++ni)
#pragma unroll
      for (int r = 0; r < 4; ++r) {
        float v = sc[ni][r] * scale;
        if (diag && (ni*16 + li > wv*16 + lg*4 + r)) v = -INFINITY;
        sc[ni][r] = v;
        mt[r] = fmaxf(mt[r], v);
      }
    // row reduce across the 16-lane group
#pragma unroll
    for (int d = 1; d < 16; d <<= 1)
#pragma unroll
      for (int r = 0; r < 4; ++r) mt[r] = fmaxf(mt[r], __shfl_xor(mt[r], d, 64));
    float corr[4], rs[4] = {0.f, 0.f, 0.f, 0.f};
#pragma unroll
    for (int r = 0; r < 4; ++r) {
      float mn = fmaxf(m_run[r], mt[r]);
      corr[r] = __expf(m_run[r] - mn);   // -inf -> 0 on first tile
      m_run[r] = mn;
    }
#pragma unroll
    for (int ni = 0; ni < 4; ++ni)
#pragma unroll
      for (int r = 0; r < 4; ++r) {
        float p = __expf(sc[ni][r] - m_run[r]);
        sc[ni][r] = p;
        rs[r] += p;
      }
#pragma unroll
    for (int d = 1; d < 16; d <<= 1)
#pragma unroll
      for (int r = 0; r < 4; ++r) rs[r] += __shfl_xor(rs[r], d, 64);
#pragma unroll
    for (int r = 0; r < 4; ++r) l_run[r] = l_run[r] * corr[r] + rs[r];
#pragma unroll
    for (int dc = 0; dc < 8; ++dc)
#pragma unroll
      for (int r = 0; r < 4; ++r) o[dc][r] *= corr[r];

    // ---- P: C-layout regs -> A-frag layout via per-wave LDS bounce ----
#pragma unroll
    for (int ni = 0; ni < 4; ++ni)
#pragma unroll
      for (int r = 0; r < 4; ++r)
        Pl[wv][(lg*4 + r)*64 + ni*16 + li] = f2bf(sc[ni][r]);
    bf16x8 pa[2];
#pragma unroll
    for (int f = 0; f < 2; ++f)
      pa[f] = *(const bf16x8*)&Pl[wv][li*64 + f*32 + lg*8];

    // ---- O += P V ----
#pragma unroll
    for (int dc = 0; dc < 8; ++dc) {
      int dh = dc*16 + li;
#pragma unroll
      for (int f = 0; f < 2; ++f) {
        int vb = (dh*128 + (f*32 + lg*8)*2) ^ ((dh & 7) << 4);
        bf16x8 vf = *(const bf16x8*)((char*)Vt + vb);
        o[dc] = mfma_bf16(pa[f], vf, o[dc]);
      }
    }
  }
  float inv[4];
#pragma unroll
  for (int r = 0; r < 4; ++r) inv[r] = 1.0f / l_run[r];
#pragma unroll
  for (int dc = 0; dc < 8; ++dc)
#pragma unroll
    for (int r = 0; r < 4; ++r) {
      size_t off = (size_t)(b*NS + q0 + wv*16 + lg*4 + r) * ND + h*NDH + dc*16 + li;
      O[off] = f2bf(o[dc][r] * inv[r]);
    }
}

// ---------------- launch ----------------
extern "C" void kernel_launch(void* const* d_in, const int* in_sizes, int n_in,
                              void* d_out, int out_size, void* d_ws, size_t ws_size,
                              hipStream_t stream) {
  const float* x  = (const float*)d_in[0];
  // d_in[1] = attn_mask (causal, handled analytically)
  const float* Wq = (const float*)d_in[2];
  const float* Wk = (const float*)d_in[3];
  const float* Wv = (const float*)d_in[4];
  const float* Wo = (const float*)d_in[5];

  char* ws = (char*)d_ws;
  const size_t SZ_MD = (size_t)NM * ND * 2;   // 33,554,432
  const size_t SZ_W  = (size_t)ND * ND * 2;   //  8,388,608
  u16* xb  = (u16*)(ws);
  u16* Qb  = (u16*)(ws + SZ_MD);
  u16* Kb  = (u16*)(ws + 2*SZ_MD);
  u16* Vb  = (u16*)(ws + 3*SZ_MD);
  u16* Ab  = (u16*)(ws + 4*SZ_MD);
  u16* Wqb = (u16*)(ws + 5*SZ_MD);
  u16* Wkb = (u16*)(ws + 5*SZ_MD + SZ_W);
  u16* Wvb = (u16*)(ws + 5*SZ_MD + 2*SZ_W);
  u16* Wob = (u16*)(ws + 5*SZ_MD + 3*SZ_W);
  float* cosT = (float*)(ws + 5*SZ_MD + 4*SZ_W);
  float* sinT = (float*)(ws + 5*SZ_MD + 4*SZ_W + (size_t)NS*64*4);
  size_t needed = 5*SZ_MD + 4*SZ_W + 2*(size_t)NS*64*4;
  if (ws_size < needed) return;  // fail loudly (harness re-validates)

  // converts
  {
    int n8 = (NM * ND) / 8;
    cvt_bf16_kernel<<<(n8 + 255)/256, 256, 0, stream>>>(x, xb, n8);
    int w8 = (ND * ND) / 8;
    cvt_bf16_kernel<<<(w8 + 255)/256, 256, 0, stream>>>(Wq, Wqb, w8);
    cvt_bf16_kernel<<<(w8 + 255)/256, 256, 0, stream>>>(Wk, Wkb, w8);
    cvt_bf16_kernel<<<(w8 + 255)/256, 256, 0, stream>>>(Wv, Wvb, w8);
    cvt_bf16_kernel<<<(w8 + 255)/256, 256, 0, stream>>>(Wo, Wob, w8);
  }
  rope_tables_kernel<<<NS, 64, 0, stream>>>(cosT, sinT);

  // projections
  const int GEMM_GRID = (NM/128) * (ND/128);   // 1024, %8==0
  gemm_bt_kernel<u16><<<GEMM_GRID, 256, 0, stream>>>(xb, Wqb, Qb, ND, ND);
  gemm_bt_kernel<u16><<<GEMM_GRID, 256, 0, stream>>>(xb, Wkb, Kb, ND, ND);
  gemm_bt_kernel<u16><<<GEMM_GRID, 256, 0, stream>>>(xb, Wvb, Vb, ND, ND);

  // RoPE on Q, K
  {
    int nthr = NM * NH * 8;
    rope_apply_kernel<<<nthr/256, 256, 0, stream>>>(Qb, cosT, sinT);
    rope_apply_kernel<<<nthr/256, 256, 0, stream>>>(Kb, cosT, sinT);
  }

  // attention
  flash_attn_kernel<<<dim3(NS/64, NB*NH), 256, 0, stream>>>(Qb, Kb, Vb, Ab);

  // output projection (fp32 out)
  gemm_bt_kernel<float><<<GEMM_GRID, 256, 0, stream>>>(Ab, Wob, (float*)d_out, ND, ND);
}

// Round 2
// 786.239 us; speedup vs baseline: 1.5705x; 1.5705x over previous
//
#include <hip/hip_runtime.h>
#include <cstdint>
#include <cmath>

#define NB 4
#define NS 2048
#define ND 2048
#define NH 16
#define NDH 128
#define NM (NB*NS)   // 8192

typedef unsigned short u16;
typedef __bf16 bf16x8 __attribute__((ext_vector_type(8)));
typedef u16    u16x8  __attribute__((ext_vector_type(8)));
typedef float  f32x4  __attribute__((ext_vector_type(4)));

__device__ __forceinline__ u16 f2bf(float f) {
  unsigned u = __float_as_uint(f);
  u += 0x7fffu + ((u >> 16) & 1u);   // RNE
  return (u16)(u >> 16);
}
__device__ __forceinline__ float bf2f(u16 h) {
  return __uint_as_float(((unsigned)h) << 16);
}
__device__ __forceinline__ void gld16(const void* g, void* l) {
  __builtin_amdgcn_global_load_lds((__attribute__((address_space(1))) void*)g,
                                   (__attribute__((address_space(3))) void*)l,
                                   16, 0, 0);
}
__device__ __forceinline__ f32x4 mfma_bf16(bf16x8 a, bf16x8 b, f32x4 c) {
  return __builtin_amdgcn_mfma_f32_16x16x32_bf16(a, b, c, 0, 0, 0);
}

// ---------------- fp32 -> bf16 convert (8 elems/thread) ----------------
__global__ void cvt_bf16_kernel(const float* __restrict__ in, u16* __restrict__ out, int n8) {
  int i = blockIdx.x * 256 + threadIdx.x;
  if (i >= n8) return;
  const float4* p = (const float4*)in + (size_t)i * 2;
  float4 a = p[0], b = p[1];
  u16x8 r;
  r[0]=f2bf(a.x); r[1]=f2bf(a.y); r[2]=f2bf(a.z); r[3]=f2bf(a.w);
  r[4]=f2bf(b.x); r[5]=f2bf(b.y); r[6]=f2bf(b.z); r[7]=f2bf(b.w);
  ((u16x8*)out)[i] = r;
}

// ---------------- RoPE tables: cos/sin [S][64] ----------------
__global__ void rope_tables_kernel(float* __restrict__ cosT, float* __restrict__ sinT) {
  int s = blockIdx.x, d = threadIdx.x;   // grid (NS), block (64)
  double inv = pow(10000.0, -(double)d / 64.0);
  float ang = (float)((double)s * inv);
  cosT[s*64 + d] = cosf(ang);
  sinT[s*64 + d] = sinf(ang);
}

// ---------------- RoPE apply, in place on bf16 [NM][ND] ----------------
__global__ void rope_apply_kernel(u16* __restrict__ X, const float* __restrict__ cosT,
                                  const float* __restrict__ sinT) {
  int idx = blockIdx.x * 256 + threadIdx.x;          // NM*NH*8 total
  int pc = idx & 7, h = (idx >> 3) & (NH - 1), m = idx >> 7;
  int s = m & (NS - 1);
  int d0 = pc * 8;
  size_t base = (size_t)m * ND + h * NDH + d0;
  u16x8 v0 = *(const u16x8*)(X + base);
  u16x8 v1 = *(const u16x8*)(X + base + 64);
  u16x8 r0, r1;
#pragma unroll
  for (int j = 0; j < 8; ++j) {
    float c  = cosT[s*64 + d0 + j];
    float sn = sinT[s*64 + d0 + j];
    float x0 = bf2f(v0[j]), x1 = bf2f(v1[j]);
    r0[j] = f2bf(x0 * c - x1 * sn);
    r1[j] = f2bf(x1 * c + x0 * sn);
  }
  *(u16x8*)(X + base)      = r0;
  *(u16x8*)(X + base + 64) = r1;
}

// ---------------- bf16 GEMM: C[M,N] = A[M,K] * Bw[N,K]^T ----------------
template <typename OutT>
__global__ __launch_bounds__(256) void gemm_bt_kernel(
    const u16* __restrict__ A, const u16* __restrict__ Bw, OutT* __restrict__ C,
    int Nd, int Kd) {
  __shared__ __align__(16) u16 As[128*32];
  __shared__ __align__(16) u16 Bs[128*32];
  int tid = threadIdx.x;
  int wave = tid >> 6, lane = tid & 63;
  int li = lane & 15, lg = lane >> 4;
  int NT = Nd >> 7;
  int cpx = gridDim.x >> 3;
  int bid = blockIdx.x;
  int swz = (bid & 7) * cpx + (bid >> 3);        // XCD-aware swizzle (grid % 8 == 0)
  int m0 = (swz / NT) << 7, n0 = (swz % NT) << 7;
  int wr = wave >> 1, wc = wave & 1;
  f32x4 acc[4][4] = {};
  const u16* Ap = A  + (size_t)(m0 + (lane >> 2)) * Kd + (lane & 3) * 8;
  const u16* Bp = Bw + (size_t)(n0 + (lane >> 2)) * Kd + (lane & 3) * 8;
  int fo = lg * 8;
  for (int k0 = 0; k0 < Kd; k0 += 32) {
#pragma unroll
    for (int it = 0; it < 2; ++it) {
      int c = it*4 + wave;
      gld16(Ap + (size_t)c*16*Kd + k0, &As[c*512]);
      gld16(Bp + (size_t)c*16*Kd + k0, &Bs[c*512]);
    }
    __syncthreads();
    bf16x8 af[4], bfr[4];
#pragma unroll
    for (int i = 0; i < 4; ++i) {
      af[i]  = *(const bf16x8*)&As[(wr*64 + i*16 + li)*32 + fo];
      bfr[i] = *(const bf16x8*)&Bs[(wc*64 + i*16 + li)*32 + fo];
    }
#pragma unroll
    for (int i = 0; i < 4; ++i)
#pragma unroll
      for (int j = 0; j < 4; ++j)
        acc[i][j] = mfma_bf16(af[i], bfr[j], acc[i][j]);
    __syncthreads();
  }
  int rbase = m0 + wr*64 + lg*4;
  int cbase = n0 + wc*64 + li;
#pragma unroll
  for (int i = 0; i < 4; ++i)
#pragma unroll
    for (int j = 0; j < 4; ++j)
#pragma unroll
      for (int r = 0; r < 4; ++r) {
        size_t off = (size_t)(rbase + i*16 + r) * Nd + (cbase + j*16);
        if constexpr (sizeof(OutT) == 2) C[off] = f2bf(acc[i][j][r]);
        else                             C[off] = acc[i][j][r];
      }
}

// ---------------- causal flash attention ----------------
// grid (B*H, S/64) with qt = 31 - blockIdx.y (heavy tiles dispatch first)
// 256 threads; wave wv owns q rows [q0+wv*16, +16)
__global__ __launch_bounds__(256, 4) void flash_attn_kernel(
    const u16* __restrict__ Q, const u16* __restrict__ K, const u16* __restrict__ V,
    u16* __restrict__ O) {
  __shared__ __align__(16) u16 Ks[64*128];   // swizzled row-major [kv][dh], filled by gld16 w/ pre-swz src
  __shared__ __align__(16) u16 Vt[128*64];   // swizzled transposed [dh][kv]
  __shared__ __align__(16) u16 Pl[4*16*64];  // per-wave P bounce (swizzled)
  int tid = threadIdx.x, wv = tid >> 6, lane = tid & 63;
  int li = lane & 15, lg = lane >> 4;
  int b = blockIdx.x >> 4, h = blockIdx.x & 15;
  int qt = (int)gridDim.y - 1 - (int)blockIdx.y;
  int q0 = qt << 6;
  const float scale = 0.08838834764831845f;  // 1/sqrt(128)

  // Q fragments, scale folded into q (bf16 re-round: well within tolerance)
  bf16x8 qf[4];
  {
    const u16* qp = Q + (size_t)(b*NS + q0 + wv*16 + li) * ND + h*NDH + lg*8;
#pragma unroll
    for (int kk = 0; kk < 4; ++kk) {
      u16x8 t = *(const u16x8*)(qp + kk*32);
      u16x8 r;
#pragma unroll
      for (int j = 0; j < 8; ++j) r[j] = f2bf(bf2f(t[j]) * scale);
      qf[kk] = *(bf16x8*)&r;
    }
  }
  f32x4 o[8] = {};
  float m_run[4], l_run[4];
#pragma unroll
  for (int r = 0; r < 4; ++r) { m_run[r] = -INFINITY; l_run[r] = 0.f; }

  const char* Kg = (const char*)(K + (size_t)b*NS*ND + h*NDH);
  const char* Vg = (const char*)(V + (size_t)b*NS*ND + h*NDH);
  const int ROWB = ND * 2;   // 4096 bytes per global row

  int p   = tid & 31;    // dh pair index: handles dh {2p,2p+1,2p+64,2p+65}
  int kvg = tid >> 5;    // kv chunk 0..7 (8 kv each)

  for (int kv0 = 0; kv0 <= q0; kv0 += 64) {
    // ---- V -> regs: column-pair loads (two 128B lines per wave inst) ----
    unsigned dlo[8], dhi[8];
    {
      const char* vrow = Vg + (size_t)(kv0 + kvg*8) * ROWB;
#pragma unroll
      for (int j = 0; j < 8; ++j) {
        dlo[j] = *(const unsigned*)(vrow + j*ROWB + p*4);         // dh 2p,2p+1
        dhi[j] = *(const unsigned*)(vrow + j*ROWB + 128 + p*4);   // dh 2p+64,2p+65
      }
    }
    // ---- K stage: gld16 linear dest + pre-swizzled global source ----
#pragma unroll
    for (int c = 0; c < 4; ++c) {
      int s = c*4096 + wv*1024 + lane*16;
      int row = s >> 8;
      int within = (s & 255) ^ ((row & 7) << 4);
      gld16(Kg + (size_t)(kv0 + row)*ROWB + within, (char*)Ks + c*4096 + wv*1024);
    }
    __syncthreads();   // Ks ready, V regs arrived, prev-iter PV done (barrier arrival)

    // ---- Vt write: in-register 8x8 repack, swizzled b128 stores ----
    {
      u16x8 rA, rB, rC, rD;
#pragma unroll
      for (int j = 0; j < 8; ++j) {
        rA[j] = (u16)dlo[j]; rB[j] = (u16)(dlo[j] >> 16);
        rC[j] = (u16)dhi[j]; rD[j] = (u16)(dhi[j] >> 16);
      }
      int a0 = ((2*p   )*128 + kvg*16) ^ (((2*p  ) & 7) << 4);
      int a1 = ((2*p+ 1)*128 + kvg*16) ^ (((2*p+1) & 7) << 4);
      int a2 = ((2*p+64)*128 + kvg*16) ^ (((2*p  ) & 7) << 4);
      int a3 = ((2*p+65)*128 + kvg*16) ^ (((2*p+1) & 7) << 4);
      *(u16x8*)((char*)Vt + a0) = rA;
      *(u16x8*)((char*)Vt + a1) = rB;
      *(u16x8*)((char*)Vt + a2) = rC;
      *(u16x8*)((char*)Vt + a3) = rD;
    }

    // ---- S = Q K^T (16q x 64kv per wave) ----
    f32x4 sc[4] = {};
#pragma unroll
    for (int ni = 0; ni < 4; ++ni) {
      int row = ni*16 + li;
#pragma unroll
      for (int kk = 0; kk < 4; ++kk) {
        int kb = (row*256 + kk*64 + lg*16) ^ ((row & 7) << 4);
        bf16x8 kf = *(const bf16x8*)((char*)Ks + kb);
        sc[ni] = mfma_bf16(qf[kk], kf, sc[ni]);
      }
    }
    __syncthreads();   // Vt ready for PV; Ks free for next iter

    // ---- online softmax ----
    bool diag = (kv0 == q0);
    float mt[4] = {-INFINITY, -INFINITY, -INFINITY, -INFINITY};
#pragma unroll
    for (int ni = 0; ni < 4; ++ni)
#pragma unroll
      for (int r = 0; r < 4; ++r) {
        float v = sc[ni][r];
        if (diag && (ni*16 + li > wv*16 + lg*4 + r)) v = -INFINITY;
        sc[ni][r] = v;
        mt[r] = fmaxf(mt[r], v);
      }
#pragma unroll
    for (int d = 1; d < 16; d <<= 1)
#pragma unroll
      for (int r = 0; r < 4; ++r) mt[r] = fmaxf(mt[r], __shfl_xor(mt[r], d, 64));
    float corr[4], rs[4] = {0.f, 0.f, 0.f, 0.f};
#pragma unroll
    for (int r = 0; r < 4; ++r) {
      float mn = fmaxf(m_run[r], mt[r]);
      corr[r] = __expf(m_run[r] - mn);
      m_run[r] = mn;
    }
#pragma unroll
    for (int ni = 0; ni < 4; ++ni)
#pragma unroll
      for (int r = 0; r < 4; ++r) {
        float pv = __expf(sc[ni][r] - m_run[r]);
        sc[ni][r] = pv;
        rs[r] += pv;
      }
#pragma unroll
    for (int d = 1; d < 16; d <<= 1)
#pragma unroll
      for (int r = 0; r < 4; ++r) rs[r] += __shfl_xor(rs[r], d, 64);
#pragma unroll
    for (int r = 0; r < 4; ++r) l_run[r] = l_run[r] * corr[r] + rs[r];
#pragma unroll
    for (int dc = 0; dc < 8; ++dc)
#pragma unroll
      for (int r = 0; r < 4; ++r) o[dc][r] *= corr[r];

    // ---- P relayout via swizzled per-wave LDS bounce ----
    {
      char* Plw = (char*)Pl + wv*2048;
#pragma unroll
      for (int ni = 0; ni < 4; ++ni)
#pragma unroll
        for (int r = 0; r < 4; ++r) {
          int rowp = lg*4 + r;
          int a = (rowp*128 + (ni*16 + li)*2) ^ ((rowp & 7) << 4);
          *(u16*)(Plw + a) = f2bf(sc[ni][r]);
        }
      bf16x8 pa[2];
#pragma unroll
      for (int f = 0; f < 2; ++f) {
        int a = (li*128 + f*64 + lg*16) ^ ((li & 7) << 4);
        pa[f] = *(const bf16x8*)(Plw + a);
      }
      // ---- O += P V ----
#pragma unroll
      for (int dc = 0; dc < 8; ++dc) {
        int dh = dc*16 + li;
#pragma unroll
        for (int f = 0; f < 2; ++f) {
          int a = (dh*128 + (f*32 + lg*8)*2) ^ ((dh & 7) << 4);
          bf16x8 vf = *(const bf16x8*)((char*)Vt + a);
          o[dc] = mfma_bf16(pa[f], vf, o[dc]);
        }
      }
    }
  }
  float inv[4];
#pragma unroll
  for (int r = 0; r < 4; ++r) inv[r] = 1.0f / l_run[r];
#pragma unroll
  for (int dc = 0; dc < 8; ++dc)
#pragma unroll
    for (int r = 0; r < 4; ++r) {
      size_t off = (size_t)(b*NS + q0 + wv*16 + lg*4 + r) * ND + h*NDH + dc*16 + li;
      O[off] = f2bf(o[dc][r] * inv[r]);
    }
}

// ---------------- launch ----------------
extern "C" void kernel_launch(void* const* d_in, const int* in_sizes, int n_in,
                              void* d_out, int out_size, void* d_ws, size_t ws_size,
                              hipStream_t stream) {
  const float* x  = (const float*)d_in[0];
  // d_in[1] = attn_mask (causal, handled analytically)
  const float* Wq = (const float*)d_in[2];
  const float* Wk = (const float*)d_in[3];
  const float* Wv = (const float*)d_in[4];
  const float* Wo = (const float*)d_in[5];

  char* ws = (char*)d_ws;
  const size_t SZ_MD = (size_t)NM * ND * 2;
  const size_t SZ_W  = (size_t)ND * ND * 2;
  u16* xb  = (u16*)(ws);
  u16* Qb  = (u16*)(ws + SZ_MD);
  u16* Kb  = (u16*)(ws + 2*SZ_MD);
  u16* Vb  = (u16*)(ws + 3*SZ_MD);
  u16* Ab  = (u16*)(ws + 4*SZ_MD);
  u16* Wqb = (u16*)(ws + 5*SZ_MD);
  u16* Wkb = (u16*)(ws + 5*SZ_MD + SZ_W);
  u16* Wvb = (u16*)(ws + 5*SZ_MD + 2*SZ_W);
  u16* Wob = (u16*)(ws + 5*SZ_MD + 3*SZ_W);
  float* cosT = (float*)(ws + 5*SZ_MD + 4*SZ_W);
  float* sinT = (float*)(ws + 5*SZ_MD + 4*SZ_W + (size_t)NS*64*4);
  size_t needed = 5*SZ_MD + 4*SZ_W + 2*(size_t)NS*64*4;
  if (ws_size < needed) return;

  {
    int n8 = (NM * ND) / 8;
    cvt_bf16_kernel<<<(n8 + 255)/256, 256, 0, stream>>>(x, xb, n8);
    int w8 = (ND * ND) / 8;
    cvt_bf16_kernel<<<(w8 + 255)/256, 256, 0, stream>>>(Wq, Wqb, w8);
    cvt_bf16_kernel<<<(w8 + 255)/256, 256, 0, stream>>>(Wk, Wkb, w8);
    cvt_bf16_kernel<<<(w8 + 255)/256, 256, 0, stream>>>(Wv, Wvb, w8);
    cvt_bf16_kernel<<<(w8 + 255)/256, 256, 0, stream>>>(Wo, Wob, w8);
  }
  rope_tables_kernel<<<NS, 64, 0, stream>>>(cosT, sinT);

  const int GEMM_GRID = (NM/128) * (ND/128);   // 1024, %8==0
  gemm_bt_kernel<u16><<<GEMM_GRID, 256, 0, stream>>>(xb, Wqb, Qb, ND, ND);
  gemm_bt_kernel<u16><<<GEMM_GRID, 256, 0, stream>>>(xb, Wkb, Kb, ND, ND);
  gemm_bt_kernel<u16><<<GEMM_GRID, 256, 0, stream>>>(xb, Wvb, Vb, ND, ND);

  {
    int nthr = NM * NH * 8;
    rope_apply_kernel<<<nthr/256, 256, 0, stream>>>(Qb, cosT, sinT);
    rope_apply_kernel<<<nthr/256, 256, 0, stream>>>(Kb, cosT, sinT);
  }

  flash_attn_kernel<<<dim3(NB*NH, NS/64), 256, 0, stream>>>(Qb, Kb, Vb, Ab);

  gemm_bt_kernel<float><<<GEMM_GRID, 256, 0, stream>>>(Ab, Wob, (float*)d_out, ND, ND);
}

// Round 3
// 678.935 us; speedup vs baseline: 1.8188x; 1.1580x over previous
//
#include <hip/hip_runtime.h>
#include <cstdint>
#include <cmath>

#define NB 4
#define NS 2048
#define ND 2048
#define NH 16
#define NDH 128
#define NM (NB*NS)   // 8192

typedef unsigned short u16;
typedef __bf16 bf16x8 __attribute__((ext_vector_type(8)));
typedef u16    u16x8  __attribute__((ext_vector_type(8)));
typedef float  f32x4  __attribute__((ext_vector_type(4)));

__device__ __forceinline__ u16 f2bf(float f) {
  unsigned u = __float_as_uint(f);
  u += 0x7fffu + ((u >> 16) & 1u);   // RNE
  return (u16)(u >> 16);
}
__device__ __forceinline__ float bf2f(u16 h) {
  return __uint_as_float(((unsigned)h) << 16);
}
__device__ __forceinline__ void gld16(const void* g, void* l) {
  __builtin_amdgcn_global_load_lds((__attribute__((address_space(1))) void*)g,
                                   (__attribute__((address_space(3))) void*)l,
                                   16, 0, 0);
}
__device__ __forceinline__ f32x4 mfma_bf16(bf16x8 a, bf16x8 b, f32x4 c) {
  return __builtin_amdgcn_mfma_f32_16x16x32_bf16(a, b, c, 0, 0, 0);
}

// ---------------- fp32 -> bf16 convert (8 elems/thread) ----------------
__global__ void cvt_bf16_kernel(const float* __restrict__ in, u16* __restrict__ out, int n8) {
  int i = blockIdx.x * 256 + threadIdx.x;
  if (i >= n8) return;
  const float4* p = (const float4*)in + (size_t)i * 2;
  float4 a = p[0], b = p[1];
  u16x8 r;
  r[0]=f2bf(a.x); r[1]=f2bf(a.y); r[2]=f2bf(a.z); r[3]=f2bf(a.w);
  r[4]=f2bf(b.x); r[5]=f2bf(b.y); r[6]=f2bf(b.z); r[7]=f2bf(b.w);
  ((u16x8*)out)[i] = r;
}

// ---------------- RoPE tables: cos/sin [S][64] ----------------
__global__ void rope_tables_kernel(float* __restrict__ cosT, float* __restrict__ sinT) {
  int s = blockIdx.x, d = threadIdx.x;   // grid (NS), block (64)
  double inv = pow(10000.0, -(double)d / 64.0);
  float ang = (float)((double)s * inv);
  cosT[s*64 + d] = cosf(ang);
  sinT[s*64 + d] = sinf(ang);
}

// ---------------- RoPE apply, in place on bf16 [NM][ND] ----------------
__global__ void rope_apply_kernel(u16* __restrict__ X, const float* __restrict__ cosT,
                                  const float* __restrict__ sinT) {
  int idx = blockIdx.x * 256 + threadIdx.x;          // NM*NH*8 total
  int pc = idx & 7, h = (idx >> 3) & (NH - 1), m = idx >> 7;
  int s = m & (NS - 1);
  int d0 = pc * 8;
  size_t base = (size_t)m * ND + h * NDH + d0;
  u16x8 v0 = *(const u16x8*)(X + base);
  u16x8 v1 = *(const u16x8*)(X + base + 64);
  u16x8 r0, r1;
#pragma unroll
  for (int j = 0; j < 8; ++j) {
    float c  = cosT[s*64 + d0 + j];
    float sn = sinT[s*64 + d0 + j];
    float x0 = bf2f(v0[j]), x1 = bf2f(v1[j]);
    r0[j] = f2bf(x0 * c - x1 * sn);
    r1[j] = f2bf(x1 * c + x0 * sn);
  }
  *(u16x8*)(X + base)      = r0;
  *(u16x8*)(X + base + 64) = r1;
}

// ---------------- bf16 GEMM: C[M,N] = A[M,K] * Bw[N,K]^T ----------------
template <typename OutT>
__global__ __launch_bounds__(256) void gemm_bt_kernel(
    const u16* __restrict__ A, const u16* __restrict__ Bw, OutT* __restrict__ C,
    int Nd, int Kd) {
  __shared__ __align__(16) u16 As[128*32];
  __shared__ __align__(16) u16 Bs[128*32];
  int tid = threadIdx.x;
  int wave = tid >> 6, lane = tid & 63;
  int li = lane & 15, lg = lane >> 4;
  int NT = Nd >> 7;
  int cpx = gridDim.x >> 3;
  int bid = blockIdx.x;
  int swz = (bid & 7) * cpx + (bid >> 3);        // XCD-aware swizzle (grid % 8 == 0)
  int m0 = (swz / NT) << 7, n0 = (swz % NT) << 7;
  int wr = wave >> 1, wc = wave & 1;
  f32x4 acc[4][4] = {};
  const u16* Ap = A  + (size_t)(m0 + (lane >> 2)) * Kd + (lane & 3) * 8;
  const u16* Bp = Bw + (size_t)(n0 + (lane >> 2)) * Kd + (lane & 3) * 8;
  int fo = lg * 8;
  for (int k0 = 0; k0 < Kd; k0 += 32) {
#pragma unroll
    for (int it = 0; it < 2; ++it) {
      int c = it*4 + wave;
      gld16(Ap + (size_t)c*16*Kd + k0, &As[c*512]);
      gld16(Bp + (size_t)c*16*Kd + k0, &Bs[c*512]);
    }
    __syncthreads();
    bf16x8 af[4], bfr[4];
#pragma unroll
    for (int i = 0; i < 4; ++i) {
      af[i]  = *(const bf16x8*)&As[(wr*64 + i*16 + li)*32 + fo];
      bfr[i] = *(const bf16x8*)&Bs[(wc*64 + i*16 + li)*32 + fo];
    }
#pragma unroll
    for (int i = 0; i < 4; ++i)
#pragma unroll
      for (int j = 0; j < 4; ++j)
        acc[i][j] = mfma_bf16(af[i], bfr[j], acc[i][j]);
    __syncthreads();
  }
  int rbase = m0 + wr*64 + lg*4;
  int cbase = n0 + wc*64 + li;
#pragma unroll
  for (int i = 0; i < 4; ++i)
#pragma unroll
    for (int j = 0; j < 4; ++j)
#pragma unroll
      for (int r = 0; r < 4; ++r) {
        size_t off = (size_t)(rbase + i*16 + r) * Nd + (cbase + j*16);
        if constexpr (sizeof(OutT) == 2) C[off] = f2bf(acc[i][j][r]);
        else                             C[off] = acc[i][j][r];
      }
}

// ---------------- causal flash attention, software-pipelined ----------------
// grid (B*H, S/64), qt = gridDim.y-1-blockIdx.y (heavy tiles first)
// 256 threads, 4 waves; wave wv owns q rows [q0+wv*16, +16)
// Double-buffered Ks/Vt; counted vmcnt(20) keeps next tile's 20 vmem ops
// (16 V dword loads + 4 K gld16) in flight across both raw barriers.
__global__ __launch_bounds__(256, 2) void flash_attn_kernel(
    const u16* __restrict__ Q, const u16* __restrict__ K, const u16* __restrict__ V,
    u16* __restrict__ O) {
  __shared__ __align__(16) u16 Ks[2*64*128];  // 2 x 16 KB, swizzled rows (gld16 pre-swz src)
  __shared__ __align__(16) u16 Vt[2*128*64];  // 2 x 16 KB, swizzled transposed [dh][kv]
  __shared__ __align__(16) u16 Pl[4*16*64];   // 8 KB per-wave P bounce (swizzled)
  int tid = threadIdx.x, wv = tid >> 6, lane = tid & 63;
  int li = lane & 15, lg = lane >> 4;
  int b = blockIdx.x >> 4, h = blockIdx.x & 15;
  int qt = (int)gridDim.y - 1 - (int)blockIdx.y;
  int q0 = qt << 6;
  const float scale = 0.08838834764831845f;   // 1/sqrt(128)

  // Q fragments, scale folded in
  bf16x8 qf[4];
  {
    const u16* qp = Q + (size_t)(b*NS + q0 + wv*16 + li) * ND + h*NDH + lg*8;
#pragma unroll
    for (int kk = 0; kk < 4; ++kk) {
      u16x8 t = *(const u16x8*)(qp + kk*32);
      u16x8 r;
#pragma unroll
      for (int j = 0; j < 8; ++j) r[j] = f2bf(bf2f(t[j]) * scale);
      qf[kk] = *(bf16x8*)&r;
    }
  }
  f32x4 o[8] = {};
  float m_run[4], l_run[4];
#pragma unroll
  for (int r = 0; r < 4; ++r) { m_run[r] = -INFINITY; l_run[r] = 0.f; }

  const char* Kg = (const char*)(K + (size_t)b*NS*ND + h*NDH);
  const char* Vg = (const char*)(V + (size_t)b*NS*ND + h*NDH);
  const int ROWB = ND * 2;   // 4096 B per global row

  int p   = tid & 31;    // dh pair: handles dh {2p,2p+1,2p+64,2p+65}
  int kvg = tid >> 5;    // kv chunk 0..7

  // issue tile loads: 16 V dword loads -> regs, 4 K gld16 -> Ks[buf]
  auto issueKV = [&](int kv0, int buf, unsigned (&dlo)[8], unsigned (&dhi)[8]) {
    const char* vrow = Vg + (size_t)(kv0 + kvg*8) * ROWB;
#pragma unroll
    for (int j = 0; j < 8; ++j) {
      dlo[j] = *(const unsigned*)(vrow + j*ROWB + p*4);
      dhi[j] = *(const unsigned*)(vrow + j*ROWB + 128 + p*4);
    }
    char* ksb = (char*)Ks + buf*16384;
#pragma unroll
    for (int c = 0; c < 4; ++c) {
      int s = c*4096 + wv*1024 + lane*16;
      int row = s >> 8;
      int within = (s & 255) ^ ((row & 7) << 4);
      gld16(Kg + (size_t)(kv0 + row)*ROWB + within, ksb + c*4096 + wv*1024);
    }
    __builtin_amdgcn_sched_barrier(0);   // pin all 20 issues before later waits
  };

  auto dostep = [&](int kv0, int buf, const unsigned (&dlo)[8], const unsigned (&dhi)[8],
                    bool diag, bool hasNext) {
    // T4: counted wait — tile-t loads (older) landed, next tile's 20 stay in flight
    if (hasNext) asm volatile("s_waitcnt vmcnt(20)" ::: "memory");
    else         asm volatile("s_waitcnt vmcnt(0)"  ::: "memory");
    __builtin_amdgcn_sched_barrier(0);
    __builtin_amdgcn_s_barrier();        // BAR-A: all waves' K(t) landed
    __builtin_amdgcn_sched_barrier(0);

    char* vtb = (char*)Vt + buf*16384;
    const char* ksb = (const char*)Ks + buf*16384;

    // Vt write: in-register 8x8 repack, swizzled b128 stores
    {
      u16x8 rA, rB, rC, rD;
#pragma unroll
      for (int j = 0; j < 8; ++j) {
        rA[j] = (u16)dlo[j]; rB[j] = (u16)(dlo[j] >> 16);
        rC[j] = (u16)dhi[j]; rD[j] = (u16)(dhi[j] >> 16);
      }
      int a0 = ((2*p   )*128 + kvg*16) ^ (((2*p  ) & 7) << 4);
      int a1 = ((2*p+ 1)*128 + kvg*16) ^ (((2*p+1) & 7) << 4);
      int a2 = ((2*p+64)*128 + kvg*16) ^ (((2*p  ) & 7) << 4);
      int a3 = ((2*p+65)*128 + kvg*16) ^ (((2*p+1) & 7) << 4);
      *(u16x8*)(vtb + a0) = rA;
      *(u16x8*)(vtb + a1) = rB;
      *(u16x8*)(vtb + a2) = rC;
      *(u16x8*)(vtb + a3) = rD;
    }

    // S = Q K^T
    f32x4 sc[4] = {};
    __builtin_amdgcn_s_setprio(1);
#pragma unroll
    for (int ni = 0; ni < 4; ++ni) {
      int row = ni*16 + li;
#pragma unroll
      for (int kk = 0; kk < 4; ++kk) {
        int kb = (row*256 + kk*64 + lg*16) ^ ((row & 7) << 4);
        bf16x8 kf = *(const bf16x8*)(ksb + kb);
        sc[ni] = mfma_bf16(qf[kk], kf, sc[ni]);
      }
    }
    __builtin_amdgcn_s_setprio(0);

    // online softmax
    float mt[4] = {-INFINITY, -INFINITY, -INFINITY, -INFINITY};
#pragma unroll
    for (int ni = 0; ni < 4; ++ni)
#pragma unroll
      for (int r = 0; r < 4; ++r) {
        float v = sc[ni][r];
        if (diag && (ni*16 + li > wv*16 + lg*4 + r)) v = -INFINITY;
        sc[ni][r] = v;
        mt[r] = fmaxf(mt[r], v);
      }
#pragma unroll
    for (int d = 1; d < 16; d <<= 1)
#pragma unroll
      for (int r = 0; r < 4; ++r) mt[r] = fmaxf(mt[r], __shfl_xor(mt[r], d, 64));
    float corr[4], rs[4] = {0.f, 0.f, 0.f, 0.f};
#pragma unroll
    for (int r = 0; r < 4; ++r) {
      float mn = fmaxf(m_run[r], mt[r]);
      corr[r] = __expf(m_run[r] - mn);
      m_run[r] = mn;
    }
#pragma unroll
    for (int ni = 0; ni < 4; ++ni)
#pragma unroll
      for (int r = 0; r < 4; ++r) {
        float pv = __expf(sc[ni][r] - m_run[r]);
        sc[ni][r] = pv;
        rs[r] += pv;
      }
#pragma unroll
    for (int d = 1; d < 16; d <<= 1)
#pragma unroll
      for (int r = 0; r < 4; ++r) rs[r] += __shfl_xor(rs[r], d, 64);
#pragma unroll
    for (int r = 0; r < 4; ++r) l_run[r] = l_run[r] * corr[r] + rs[r];
#pragma unroll
    for (int dc = 0; dc < 8; ++dc)
#pragma unroll
      for (int r = 0; r < 4; ++r) o[dc][r] *= corr[r];

    // P relayout via swizzled per-wave LDS bounce (same-wave, no barrier needed)
    bf16x8 pa[2];
    {
      char* Plw = (char*)Pl + wv*2048;
#pragma unroll
      for (int ni = 0; ni < 4; ++ni)
#pragma unroll
        for (int r = 0; r < 4; ++r) {
          int rowp = lg*4 + r;
          int a = (rowp*128 + (ni*16 + li)*2) ^ (((rowp ^ (rowp >> 3)) & 7) << 4);
          *(u16*)(Plw + a) = f2bf(sc[ni][r]);
        }
#pragma unroll
      for (int f = 0; f < 2; ++f) {
        int a = (li*128 + f*64 + lg*16) ^ (((li ^ (li >> 3)) & 7) << 4);
        pa[f] = *(const bf16x8*)(Plw + a);
      }
    }

    asm volatile("s_waitcnt lgkmcnt(0)" ::: "memory");  // my Vt writes done
    __builtin_amdgcn_sched_barrier(0);
    __builtin_amdgcn_s_barrier();        // BAR-B: all waves' Vt[buf] visible
    __builtin_amdgcn_sched_barrier(0);

    // O += P V
    __builtin_amdgcn_s_setprio(1);
#pragma unroll
    for (int dc = 0; dc < 8; ++dc) {
      int dh = dc*16 + li;
#pragma unroll
      for (int f = 0; f < 2; ++f) {
        int a = (dh*128 + (f*32 + lg*8)*2) ^ ((dh & 7) << 4);
        bf16x8 vf = *(const bf16x8*)(vtb + a);
        o[dc] = mfma_bf16(pa[f], vf, o[dc]);
      }
    }
    __builtin_amdgcn_s_setprio(0);
  };

  unsigned dloA[8], dhiA[8], dloB[8], dhiB[8];
  issueKV(0, 0, dloA, dhiA);
  for (int t = 0; ; t += 2) {
    bool h1 = (t < qt);
    if (h1) issueKV((t+1)*64, 1, dloB, dhiB);
    dostep(t*64, 0, dloA, dhiA, t == qt, h1);
    if (!h1) break;
    bool h2 = (t+1 < qt);
    if (h2) issueKV((t+2)*64, 0, dloA, dhiA);
    dostep((t+1)*64, 1, dloB, dhiB, (t+1) == qt, h2);
    if (!h2) break;
  }

  float inv[4];
#pragma unroll
  for (int r = 0; r < 4; ++r) inv[r] = 1.0f / l_run[r];
#pragma unroll
  for (int dc = 0; dc < 8; ++dc)
#pragma unroll
    for (int r = 0; r < 4; ++r) {
      size_t off = (size_t)(b*NS + q0 + wv*16 + lg*4 + r) * ND + h*NDH + dc*16 + li;
      O[off] = f2bf(o[dc][r] * inv[r]);
    }
}

// ---------------- launch ----------------
extern "C" void kernel_launch(void* const* d_in, const int* in_sizes, int n_in,
                              void* d_out, int out_size, void* d_ws, size_t ws_size,
                              hipStream_t stream) {
  const float* x  = (const float*)d_in[0];
  // d_in[1] = attn_mask (causal, handled analytically)
  const float* Wq = (const float*)d_in[2];
  const float* Wk = (const float*)d_in[3];
  const float* Wv = (const float*)d_in[4];
  const float* Wo = (const float*)d_in[5];

  char* ws = (char*)d_ws;
  const size_t SZ_MD = (size_t)NM * ND * 2;
  const size_t SZ_W  = (size_t)ND * ND * 2;
  u16* xb  = (u16*)(ws);
  u16* Qb  = (u16*)(ws + SZ_MD);
  u16* Kb  = (u16*)(ws + 2*SZ_MD);
  u16* Vb  = (u16*)(ws + 3*SZ_MD);
  u16* Ab  = (u16*)(ws + 4*SZ_MD);
  u16* Wqb = (u16*)(ws + 5*SZ_MD);
  u16* Wkb = (u16*)(ws + 5*SZ_MD + SZ_W);
  u16* Wvb = (u16*)(ws + 5*SZ_MD + 2*SZ_W);
  u16* Wob = (u16*)(ws + 5*SZ_MD + 3*SZ_W);
  float* cosT = (float*)(ws + 5*SZ_MD + 4*SZ_W);
  float* sinT = (float*)(ws + 5*SZ_MD + 4*SZ_W + (size_t)NS*64*4);
  size_t needed = 5*SZ_MD + 4*SZ_W + 2*(size_t)NS*64*4;
  if (ws_size < needed) return;

  {
    int n8 = (NM * ND) / 8;
    cvt_bf16_kernel<<<(n8 + 255)/256, 256, 0, stream>>>(x, xb, n8);
    int w8 = (ND * ND) / 8;
    cvt_bf16_kernel<<<(w8 + 255)/256, 256, 0, stream>>>(Wq, Wqb, w8);
    cvt_bf16_kernel<<<(w8 + 255)/256, 256, 0, stream>>>(Wk, Wkb, w8);
    cvt_bf16_kernel<<<(w8 + 255)/256, 256, 0, stream>>>(Wv, Wvb, w8);
    cvt_bf16_kernel<<<(w8 + 255)/256, 256, 0, stream>>>(Wo, Wob, w8);
  }
  rope_tables_kernel<<<NS, 64, 0, stream>>>(cosT, sinT);

  const int GEMM_GRID = (NM/128) * (ND/128);   // 1024, %8==0
  gemm_bt_kernel<u16><<<GEMM_GRID, 256, 0, stream>>>(xb, Wqb, Qb, ND, ND);
  gemm_bt_kernel<u16><<<GEMM_GRID, 256, 0, stream>>>(xb, Wkb, Kb, ND, ND);
  gemm_bt_kernel<u16><<<GEMM_GRID, 256, 0, stream>>>(xb, Wvb, Vb, ND, ND);

  {
    int nthr = NM * NH * 8;
    rope_apply_kernel<<<nthr/256, 256, 0, stream>>>(Qb, cosT, sinT);
    rope_apply_kernel<<<nthr/256, 256, 0, stream>>>(Kb, cosT, sinT);
  }

  flash_attn_kernel<<<dim3(NB*NH, NS/64), 256, 0, stream>>>(Qb, Kb, Vb, Ab);

  gemm_bt_kernel<float><<<GEMM_GRID, 256, 0, stream>>>(Ab, Wob, (float*)d_out, ND, ND);
}

// Round 4
// 521.204 us; speedup vs baseline: 2.3692x; 1.3026x over previous
//
#include <hip/hip_runtime.h>
#include <cstdint>
#include <cmath>

#define NB 4
#define NS 2048
#define ND 2048
#define NH 16
#define NDH 128
#define NM (NB*NS)   // 8192

typedef unsigned short u16;
typedef __bf16 bf16x8 __attribute__((ext_vector_type(8)));
typedef u16    u16x8  __attribute__((ext_vector_type(8)));
typedef float  f32x4  __attribute__((ext_vector_type(4)));

__device__ __forceinline__ u16 f2bf(float f) {
  unsigned u = __float_as_uint(f);
  u += 0x7fffu + ((u >> 16) & 1u);   // RNE
  return (u16)(u >> 16);
}
__device__ __forceinline__ float bf2f(u16 h) {
  return __uint_as_float(((unsigned)h) << 16);
}
__device__ __forceinline__ void gld16(const void* g, void* l) {
  __builtin_amdgcn_global_load_lds((__attribute__((address_space(1))) void*)g,
                                   (__attribute__((address_space(3))) void*)l,
                                   16, 0, 0);
}
__device__ __forceinline__ f32x4 mfma_bf16(bf16x8 a, bf16x8 b, f32x4 c) {
  return __builtin_amdgcn_mfma_f32_16x16x32_bf16(a, b, c, 0, 0, 0);
}

// ---------------- fp32 -> bf16 convert (8 elems/thread) ----------------
__global__ void cvt_bf16_kernel(const float* __restrict__ in, u16* __restrict__ out, int n8) {
  int i = blockIdx.x * 256 + threadIdx.x;
  if (i >= n8) return;
  const float4* p = (const float4*)in + (size_t)i * 2;
  float4 a = p[0], b = p[1];
  u16x8 r;
  r[0]=f2bf(a.x); r[1]=f2bf(a.y); r[2]=f2bf(a.z); r[3]=f2bf(a.w);
  r[4]=f2bf(b.x); r[5]=f2bf(b.y); r[6]=f2bf(b.z); r[7]=f2bf(b.w);
  ((u16x8*)out)[i] = r;
}

// ---------------- RoPE tables: cos/sin [S][64] ----------------
__global__ void rope_tables_kernel(float* __restrict__ cosT, float* __restrict__ sinT) {
  int s = blockIdx.x, d = threadIdx.x;
  double inv = pow(10000.0, -(double)d / 64.0);
  float ang = (float)((double)s * inv);
  cosT[s*64 + d] = cosf(ang);
  sinT[s*64 + d] = sinf(ang);
}

// ---------------- RoPE apply, in place on bf16 [NM][ND] ----------------
__global__ void rope_apply_kernel(u16* __restrict__ X, const float* __restrict__ cosT,
                                  const float* __restrict__ sinT) {
  int idx = blockIdx.x * 256 + threadIdx.x;
  int pc = idx & 7, h = (idx >> 3) & (NH - 1), m = idx >> 7;
  int s = m & (NS - 1);
  int d0 = pc * 8;
  size_t base = (size_t)m * ND + h * NDH + d0;
  u16x8 v0 = *(const u16x8*)(X + base);
  u16x8 v1 = *(const u16x8*)(X + base + 64);
  u16x8 r0, r1;
#pragma unroll
  for (int j = 0; j < 8; ++j) {
    float c  = cosT[s*64 + d0 + j];
    float sn = sinT[s*64 + d0 + j];
    float x0 = bf2f(v0[j]), x1 = bf2f(v1[j]);
    r0[j] = f2bf(x0 * c - x1 * sn);
    r1[j] = f2bf(x1 * c + x0 * sn);
  }
  *(u16x8*)(X + base)      = r0;
  *(u16x8*)(X + base + 64) = r1;
}

// ---------------- bf16 GEMM, 256x256 tile, 8-phase pipelined ----------------
// C[M,N] = A[M,K] * Bw[N,K]^T.  512 threads = 8 waves (2 m x 4 n).
// LDS: per matrix 2 dbuf x 2 ks-slab x [256 rows][32 cols] bf16 = 64 KB; total 128 KB.
// Slab swizzle: byte c (0..63) ^= ((row&3)<<4); staged via gld16 with
// pre-swizzled global source (linear LDS dest).  Stage-unit = 1 ks-half of
// A or B (2 gld16/thread); 1 unit issued per phase; consumption lead = 5-6
// phases; uniform s_waitcnt vmcnt(8) per phase (newest 4 units in flight).
#define G_PHASE(BUF, KS, MH, LOADB, STAGE) do {                                   \
  bf16x8 af[4];                                                                   \
  _Pragma("unroll")                                                               \
  for (int mf = 0; mf < 4; ++mf)                                                  \
    af[mf] = *(const bf16x8*)(Asb + (BUF)*32768 + (KS)*16384 + arow + ((MH)*4+mf)*1024); \
  if (LOADB) {                                                                    \
    _Pragma("unroll")                                                             \
    for (int nf = 0; nf < 4; ++nf)                                                \
      bfr[nf] = *(const bf16x8*)(Bsb + (BUF)*32768 + (KS)*16384 + brow + nf*1024); \
  }                                                                               \
  STAGE;                                                                          \
  asm volatile("s_waitcnt vmcnt(8)" ::: "memory");                                \
  __builtin_amdgcn_sched_barrier(0);                                              \
  __builtin_amdgcn_s_barrier();                                                   \
  __builtin_amdgcn_s_setprio(1);                                                  \
  _Pragma("unroll")                                                               \
  for (int mf = 0; mf < 4; ++mf)                                                  \
    _Pragma("unroll")                                                             \
    for (int nf = 0; nf < 4; ++nf)                                                \
      acc[(MH)*4+mf][nf] = mfma_bf16(af[mf], bfr[nf], acc[(MH)*4+mf][nf]);        \
  __builtin_amdgcn_s_setprio(0);                                                  \
  __builtin_amdgcn_s_barrier();                                                   \
} while (0)

template <typename OutT>
__global__ __launch_bounds__(512, 1) void gemm256_kernel(
    const u16* __restrict__ A, const u16* __restrict__ Bw, OutT* __restrict__ C,
    int Nd, int Kd) {
  __shared__ __align__(16) char Asb[65536];
  __shared__ __align__(16) char Bsb[65536];
  int tid = threadIdx.x;
  int wave = tid >> 6, lane = tid & 63;
  int li = lane & 15, lg = lane >> 4;
  int wr = wave >> 2, wc = wave & 3;           // 2 x 4 wave grid
  int NTn = Nd >> 8;
  int cpx = (int)gridDim.x >> 3;               // grid % 8 == 0
  int bid = (int)blockIdx.x;
  int swz = (bid & 7) * cpx + (bid >> 3);      // XCD-aware, bijective
  int m0 = (swz / NTn) << 8, n0 = (swz % NTn) << 8;

  // ds_read per-lane bases (byte offsets within a slab)
  int rswz = (lg * 16) ^ ((li & 3) << 4);
  int arow = (wr * 128 + li) * 64 + rswz;      // + mfrag*1024
  int brow = (wc *  64 + li) * 64 + rswz;      // + nfrag*1024

  // staging per-lane constants
  int srow = wave * 16 + (lane >> 2);          // 0..127
  int scswz = ((lane & 3) * 16) ^ ((srow & 3) << 4);
  size_t rowB = (size_t)Kd * 2;                // bytes per global row
  const char* Asrc = (const char*)A + (size_t)(m0 + srow) * rowB + scswz;
  const char* Bsrc = (const char*)Bw + (size_t)(n0 + srow) * rowB + scswz;
  char* Adst = Asb + wave * 1024;              // + buf*32768 + ks*16384 (+8192 half2)
  char* Bdst = Bsb + wave * 1024;
  size_t half2 = rowB << 7;                    // 128 rows

  auto stageA = [&](int buf, int ks, int tile) {
    const char* s = Asrc + (size_t)tile * 128 + ks * 64;
    char* d = Adst + buf * 32768 + ks * 16384;
    gld16(s, d);
    gld16(s + half2, d + 8192);
  };
  auto stageB = [&](int buf, int ks, int tile) {
    const char* s = Bsrc + (size_t)tile * 128 + ks * 64;
    char* d = Bdst + buf * 32768 + ks * 16384;
    gld16(s, d);
    gld16(s + half2, d + 8192);
  };

  f32x4 acc[8][4] = {};
  bf16x8 bfr[4];

  int NKT = Kd >> 6;          // K-tiles of 64
  int NIT = NKT >> 1;         // 2 tiles per iteration

  // prologue: tile0 fully + tile1 ks0
  stageA(0, 0, 0); stageA(0, 1, 0); stageB(0, 0, 0); stageB(0, 1, 0);
  stageA(1, 0, 1); stageB(1, 0, 1);
  asm volatile("s_waitcnt vmcnt(4)" ::: "memory");   // tile0 landed; t1-ks0 in flight
  __builtin_amdgcn_sched_barrier(0);
  __builtin_amdgcn_s_barrier();

  for (int j = 0; j < NIT; ++j) {
    int t1  = 2*j + 1;
    int tn0 = (2*j + 2) & (NKT - 1);   // wraps on final iters (garbage, unconsumed)
    int tn1 = (2*j + 3) & (NKT - 1);
    G_PHASE(0, 0, 0, true,  { stageA(1, 1, t1);  });
    G_PHASE(0, 0, 1, false, { stageB(1, 1, t1);  });
    G_PHASE(0, 1, 1, true,  { stageA(0, 0, tn0); });
    G_PHASE(0, 1, 0, false, { stageB(0, 0, tn0); });
    G_PHASE(1, 0, 0, true,  { stageA(0, 1, tn0); });
    G_PHASE(1, 0, 1, false, { stageB(0, 1, tn0); });
    G_PHASE(1, 1, 1, true,  { stageA(1, 0, tn1); });
    G_PHASE(1, 1, 0, false, { stageB(1, 0, tn1); });
  }
  asm volatile("s_waitcnt vmcnt(0)" ::: "memory");   // drain dangling stages

  // epilogue: C layout col=lane&15, row=(lane>>4)*4+reg  [m89/m91]
  int rbase = m0 + wr*128 + lg*4;
  int cbase = n0 + wc*64 + li;
#pragma unroll
  for (int am = 0; am < 8; ++am)
#pragma unroll
    for (int nf = 0; nf < 4; ++nf)
#pragma unroll
      for (int r = 0; r < 4; ++r) {
        size_t off = (size_t)(rbase + am*16 + r) * Nd + (cbase + nf*16);
        if constexpr (sizeof(OutT) == 2) C[off] = f2bf(acc[am][nf][r]);
        else                             C[off] = acc[am][nf][r];
      }
}

// ---------------- causal flash attention, software-pipelined ----------------
__global__ __launch_bounds__(256, 2) void flash_attn_kernel(
    const u16* __restrict__ Q, const u16* __restrict__ K, const u16* __restrict__ V,
    u16* __restrict__ O) {
  __shared__ __align__(16) u16 Ks[2*64*128];
  __shared__ __align__(16) u16 Vt[2*128*64];
  __shared__ __align__(16) u16 Pl[4*16*64];
  int tid = threadIdx.x, wv = tid >> 6, lane = tid & 63;
  int li = lane & 15, lg = lane >> 4;
  int b = blockIdx.x >> 4, h = blockIdx.x & 15;
  int qt = (int)gridDim.y - 1 - (int)blockIdx.y;
  int q0 = qt << 6;
  const float scale = 0.08838834764831845f;

  bf16x8 qf[4];
  {
    const u16* qp = Q + (size_t)(b*NS + q0 + wv*16 + li) * ND + h*NDH + lg*8;
#pragma unroll
    for (int kk = 0; kk < 4; ++kk) {
      u16x8 t = *(const u16x8*)(qp + kk*32);
      u16x8 r;
#pragma unroll
      for (int j = 0; j < 8; ++j) r[j] = f2bf(bf2f(t[j]) * scale);
      qf[kk] = *(bf16x8*)&r;
    }
  }
  f32x4 o[8] = {};
  float m_run[4], l_run[4];
#pragma unroll
  for (int r = 0; r < 4; ++r) { m_run[r] = -INFINITY; l_run[r] = 0.f; }

  const char* Kg = (const char*)(K + (size_t)b*NS*ND + h*NDH);
  const char* Vg = (const char*)(V + (size_t)b*NS*ND + h*NDH);
  const int ROWB = ND * 2;

  int p   = tid & 31;
  int kvg = tid >> 5;

  auto issueKV = [&](int kv0, int buf, unsigned (&dlo)[8], unsigned (&dhi)[8]) {
    const char* vrow = Vg + (size_t)(kv0 + kvg*8) * ROWB;
#pragma unroll
    for (int j = 0; j < 8; ++j) {
      dlo[j] = *(const unsigned*)(vrow + j*ROWB + p*4);
      dhi[j] = *(const unsigned*)(vrow + j*ROWB + 128 + p*4);
    }
    char* ksb = (char*)Ks + buf*16384;
#pragma unroll
    for (int c = 0; c < 4; ++c) {
      int s = c*4096 + wv*1024 + lane*16;
      int row = s >> 8;
      int within = (s & 255) ^ ((row & 7) << 4);
      gld16(Kg + (size_t)(kv0 + row)*ROWB + within, ksb + c*4096 + wv*1024);
    }
    __builtin_amdgcn_sched_barrier(0);
  };

  auto dostep = [&](int kv0, int buf, const unsigned (&dlo)[8], const unsigned (&dhi)[8],
                    bool diag, bool hasNext) {
    if (hasNext) asm volatile("s_waitcnt vmcnt(20)" ::: "memory");
    else         asm volatile("s_waitcnt vmcnt(0)"  ::: "memory");
    __builtin_amdgcn_sched_barrier(0);
    __builtin_amdgcn_s_barrier();
    __builtin_amdgcn_sched_barrier(0);

    char* vtb = (char*)Vt + buf*16384;
    const char* ksb = (const char*)Ks + buf*16384;

    {
      u16x8 rA, rB, rC, rD;
#pragma unroll
      for (int j = 0; j < 8; ++j) {
        rA[j] = (u16)dlo[j]; rB[j] = (u16)(dlo[j] >> 16);
        rC[j] = (u16)dhi[j]; rD[j] = (u16)(dhi[j] >> 16);
      }
      int a0 = ((2*p   )*128 + kvg*16) ^ (((2*p  ) & 7) << 4);
      int a1 = ((2*p+ 1)*128 + kvg*16) ^ (((2*p+1) & 7) << 4);
      int a2 = ((2*p+64)*128 + kvg*16) ^ (((2*p  ) & 7) << 4);
      int a3 = ((2*p+65)*128 + kvg*16) ^ (((2*p+1) & 7) << 4);
      *(u16x8*)(vtb + a0) = rA;
      *(u16x8*)(vtb + a1) = rB;
      *(u16x8*)(vtb + a2) = rC;
      *(u16x8*)(vtb + a3) = rD;
    }

    f32x4 sc[4] = {};
    __builtin_amdgcn_s_setprio(1);
#pragma unroll
    for (int ni = 0; ni < 4; ++ni) {
      int row = ni*16 + li;
#pragma unroll
      for (int kk = 0; kk < 4; ++kk) {
        int kb = (row*256 + kk*64 + lg*16) ^ ((row & 7) << 4);
        bf16x8 kf = *(const bf16x8*)(ksb + kb);
        sc[ni] = mfma_bf16(qf[kk], kf, sc[ni]);
      }
    }
    __builtin_amdgcn_s_setprio(0);

    float mt[4] = {-INFINITY, -INFINITY, -INFINITY, -INFINITY};
#pragma unroll
    for (int ni = 0; ni < 4; ++ni)
#pragma unroll
      for (int r = 0; r < 4; ++r) {
        float v = sc[ni][r];
        if (diag && (ni*16 + li > wv*16 + lg*4 + r)) v = -INFINITY;
        sc[ni][r] = v;
        mt[r] = fmaxf(mt[r], v);
      }
#pragma unroll
    for (int d = 1; d < 16; d <<= 1)
#pragma unroll
      for (int r = 0; r < 4; ++r) mt[r] = fmaxf(mt[r], __shfl_xor(mt[r], d, 64));
    float corr[4], rs[4] = {0.f, 0.f, 0.f, 0.f};
#pragma unroll
    for (int r = 0; r < 4; ++r) {
      float mn = fmaxf(m_run[r], mt[r]);
      corr[r] = __expf(m_run[r] - mn);
      m_run[r] = mn;
    }
#pragma unroll
    for (int ni = 0; ni < 4; ++ni)
#pragma unroll
      for (int r = 0; r < 4; ++r) {
        float pv = __expf(sc[ni][r] - m_run[r]);
        sc[ni][r] = pv;
        rs[r] += pv;
      }
#pragma unroll
    for (int d = 1; d < 16; d <<= 1)
#pragma unroll
      for (int r = 0; r < 4; ++r) rs[r] += __shfl_xor(rs[r], d, 64);
#pragma unroll
    for (int r = 0; r < 4; ++r) l_run[r] = l_run[r] * corr[r] + rs[r];
#pragma unroll
    for (int dc = 0; dc < 8; ++dc)
#pragma unroll
      for (int r = 0; r < 4; ++r) o[dc][r] *= corr[r];

    bf16x8 pa[2];
    {
      char* Plw = (char*)Pl + wv*2048;
#pragma unroll
      for (int ni = 0; ni < 4; ++ni)
#pragma unroll
        for (int r = 0; r < 4; ++r) {
          int rowp = lg*4 + r;
          int a = (rowp*128 + (ni*16 + li)*2) ^ (((rowp ^ (rowp >> 3)) & 7) << 4);
          *(u16*)(Plw + a) = f2bf(sc[ni][r]);
        }
#pragma unroll
      for (int f = 0; f < 2; ++f) {
        int a = (li*128 + f*64 + lg*16) ^ (((li ^ (li >> 3)) & 7) << 4);
        pa[f] = *(const bf16x8*)(Plw + a);
      }
    }

    asm volatile("s_waitcnt lgkmcnt(0)" ::: "memory");
    __builtin_amdgcn_sched_barrier(0);
    __builtin_amdgcn_s_barrier();
    __builtin_amdgcn_sched_barrier(0);

    __builtin_amdgcn_s_setprio(1);
#pragma unroll
    for (int dc = 0; dc < 8; ++dc) {
      int dh = dc*16 + li;
#pragma unroll
      for (int f = 0; f < 2; ++f) {
        int a = (dh*128 + (f*32 + lg*8)*2) ^ ((dh & 7) << 4);
        bf16x8 vf = *(const bf16x8*)(vtb + a);
        o[dc] = mfma_bf16(pa[f], vf, o[dc]);
      }
    }
    __builtin_amdgcn_s_setprio(0);
  };

  unsigned dloA[8], dhiA[8], dloB[8], dhiB[8];
  issueKV(0, 0, dloA, dhiA);
  for (int t = 0; ; t += 2) {
    bool h1 = (t < qt);
    if (h1) issueKV((t+1)*64, 1, dloB, dhiB);
    dostep(t*64, 0, dloA, dhiA, t == qt, h1);
    if (!h1) break;
    bool h2 = (t+1 < qt);
    if (h2) issueKV((t+2)*64, 0, dloA, dhiA);
    dostep((t+1)*64, 1, dloB, dhiB, (t+1) == qt, h2);
    if (!h2) break;
  }

  float inv[4];
#pragma unroll
  for (int r = 0; r < 4; ++r) inv[r] = 1.0f / l_run[r];
#pragma unroll
  for (int dc = 0; dc < 8; ++dc)
#pragma unroll
    for (int r = 0; r < 4; ++r) {
      size_t off = (size_t)(b*NS + q0 + wv*16 + lg*4 + r) * ND + h*NDH + dc*16 + li;
      O[off] = f2bf(o[dc][r] * inv[r]);
    }
}

// ---------------- launch ----------------
extern "C" void kernel_launch(void* const* d_in, const int* in_sizes, int n_in,
                              void* d_out, int out_size, void* d_ws, size_t ws_size,
                              hipStream_t stream) {
  const float* x  = (const float*)d_in[0];
  // d_in[1] = attn_mask (causal, handled analytically)
  const float* Wq = (const float*)d_in[2];
  const float* Wk = (const float*)d_in[3];
  const float* Wv = (const float*)d_in[4];
  const float* Wo = (const float*)d_in[5];

  char* ws = (char*)d_ws;
  const size_t SZ_MD = (size_t)NM * ND * 2;
  const size_t SZ_W  = (size_t)ND * ND * 2;
  u16* xb  = (u16*)(ws);
  u16* Qb  = (u16*)(ws + SZ_MD);
  u16* Kb  = (u16*)(ws + 2*SZ_MD);
  u16* Vb  = (u16*)(ws + 3*SZ_MD);
  u16* Ab  = (u16*)(ws + 4*SZ_MD);
  u16* Wqb = (u16*)(ws + 5*SZ_MD);
  u16* Wkb = (u16*)(ws + 5*SZ_MD + SZ_W);
  u16* Wvb = (u16*)(ws + 5*SZ_MD + 2*SZ_W);
  u16* Wob = (u16*)(ws + 5*SZ_MD + 3*SZ_W);
  float* cosT = (float*)(ws + 5*SZ_MD + 4*SZ_W);
  float* sinT = (float*)(ws + 5*SZ_MD + 4*SZ_W + (size_t)NS*64*4);
  size_t needed = 5*SZ_MD + 4*SZ_W + 2*(size_t)NS*64*4;
  if (ws_size < needed) return;

  {
    int n8 = (NM * ND) / 8;
    cvt_bf16_kernel<<<(n8 + 255)/256, 256, 0, stream>>>(x, xb, n8);
    int w8 = (ND * ND) / 8;
    cvt_bf16_kernel<<<(w8 + 255)/256, 256, 0, stream>>>(Wq, Wqb, w8);
    cvt_bf16_kernel<<<(w8 + 255)/256, 256, 0, stream>>>(Wk, Wkb, w8);
    cvt_bf16_kernel<<<(w8 + 255)/256, 256, 0, stream>>>(Wv, Wvb, w8);
    cvt_bf16_kernel<<<(w8 + 255)/256, 256, 0, stream>>>(Wo, Wob, w8);
  }
  rope_tables_kernel<<<NS, 64, 0, stream>>>(cosT, sinT);

  const int GEMM_GRID = (NM/256) * (ND/256);   // 256, %8==0
  gemm256_kernel<u16><<<GEMM_GRID, 512, 0, stream>>>(xb, Wqb, Qb, ND, ND);
  gemm256_kernel<u16><<<GEMM_GRID, 512, 0, stream>>>(xb, Wkb, Kb, ND, ND);
  gemm256_kernel<u16><<<GEMM_GRID, 512, 0, stream>>>(xb, Wvb, Vb, ND, ND);

  {
    int nthr = NM * NH * 8;
    rope_apply_kernel<<<nthr/256, 256, 0, stream>>>(Qb, cosT, sinT);
    rope_apply_kernel<<<nthr/256, 256, 0, stream>>>(Kb, cosT, sinT);
  }

  flash_attn_kernel<<<dim3(NB*NH, NS/64), 256, 0, stream>>>(Qb, Kb, Vb, Ab);

  gemm256_kernel<float><<<GEMM_GRID, 512, 0, stream>>>(Ab, Wob, (float*)d_out, ND, ND);
}